// Round 12
// baseline (155.477 us; speedup 1.0000x reference)
//
#include <hip/hip_runtime.h>

#define NB 32
#define NN 500
#define HIN 64
#define HHID 16
#define NHEAD 8
#define NVALID 400
#define MAXK 128
#define NEG_INF -1e20f

// ---------------- K0: fused layer-1 projection (blocks 0..1023) + neighbor-list build (blocks 1024..5023) ----
__global__ __launch_bounds__(256) void k_pre(const float* __restrict__ A,
                                             int* __restrict__ nbr, int* __restrict__ cnt,
                                             const float* __restrict__ x, const float* __restrict__ w1,
                                             const float* __restrict__ as1, const float* __restrict__ ad1,
                                             float* __restrict__ h1p, float* __restrict__ e1s,
                                             float* __restrict__ e1d)
{
    int bid = blockIdx.x;
    if (bid >= 1024) {
        // ---- neighbor build: 4 rows per block, one wave per row ----
        int row = (bid - 1024) * 4 + (threadIdx.x >> 6);   // b*NN + n
        int lane = threadIdx.x & 63;
        const float4* arow4 = (const float4*)(A + (size_t)row * NN);  // 125 float4, 16B aligned
        int* np = nbr + (size_t)row * MAXK;
        int c = 0;
#pragma unroll
        for (int it = 0; it < 2; ++it) {
            int idx = it * 64 + lane;
            float4 av;
            if (idx < 125) av = arow4[idx];
            else { av.x = av.y = av.z = av.w = 0.f; }
            bool v0 = av.x > 0.f, v1 = av.y > 0.f, v2 = av.z > 0.f, v3 = av.w > 0.f;
            unsigned long long b0 = __ballot(v0), b1 = __ballot(v1);
            unsigned long long b2 = __ballot(v2), b3 = __ballot(v3);
            unsigned long long below = (1ull << lane) - 1ull;
            int p = c + __popcll(b0 & below) + __popcll(b1 & below)
                      + __popcll(b2 & below) + __popcll(b3 & below);
            int col = idx * 4;
            if (v0 && p < MAXK) np[p] = col;     p += (int)v0;
            if (v1 && p < MAXK) np[p] = col + 1; p += (int)v1;
            if (v2 && p < MAXK) np[p] = col + 2; p += (int)v2;
            if (v3 && p < MAXK) np[p] = col + 3; p += (int)v3;
            c += (int)(__popcll(b0) + __popcll(b1) + __popcll(b2) + __popcll(b3));
        }
        if (lane == 0) cnt[row] = c < MAXK ? c : MAXK;
        return;
    }
    // ---- layer-1 projection (single-stage) ----
    int pb = bid;
    int b = pb >> 5, chunk = pb & 31;
    int t = threadIdx.x, slot = t >> 7, lane = t & 127;
    int h = lane >> 4, o = lane & 15;
    float wreg[64];
#pragma unroll
    for (int f = 0; f < 64; ++f) wreg[f] = w1[h * 1024 + f * 16 + o];
    float as_r = as1[h * 16 + o], ad_r = ad1[h * 16 + o];
    __shared__ __align__(16) float xs[16][64];
    {
        int node = chunk * 16 + (t >> 4);
        float4 v = make_float4(0.f, 0.f, 0.f, 0.f);
        if (node < NN) v = *(const float4*)&x[(size_t)(b * NN + node) * HIN + ((t * 4) & 63)];
        *(float4*)&xs[t >> 4][(t * 4) & 63] = v;
    }
    __syncthreads();
    for (int i = 0; i < 8; ++i) {
        int n = chunk * 16 + i * 2 + slot;
        if (n < NN) {
            const float* xrow = xs[i * 2 + slot];
            float acc = 0.f;
#pragma unroll
            for (int f4 = 0; f4 < 16; ++f4) {
                float4 xv = *(const float4*)&xrow[f4 * 4];
                acc += xv.x * wreg[f4 * 4] + xv.y * wreg[f4 * 4 + 1]
                     + xv.z * wreg[f4 * 4 + 2] + xv.w * wreg[f4 * 4 + 3];
            }
            h1p[(size_t)(b * NN + n) * 128 + lane] = acc;      // [b][n][h*16+o]
            float vs = acc * as_r, vd = acc * ad_r;
#pragma unroll
            for (int m = 1; m < 16; m <<= 1) { vs += __shfl_xor(vs, m); vd += __shfl_xor(vd, m); }
            if (o == 0) {
                e1s[(size_t)(b * NN + n) * 8 + h] = vs;        // [b][n][h]
                e1d[(size_t)(b * NN + n) * 8 + h] = vd;
            }
        }
    }
}

// ---------------- K1: fused layer-1 aggregate + ELU + streamed layer-2 projection ----------------
// R11 structure (2 waves/row, 1 barrier) + latency-chain cuts:
//  - nbr loaded UNCONDITIONALLY (in-bounds; entries >= K never used) -> cnt and nbr loads overlap
//  - first-8 h1p lines prefetched (shfl-broadcast addrs, clamped) BEFORE the e-phase ->
//    first gather group's latency hides under e-gather + softmax. FP order bitwise identical.
__global__ __launch_bounds__(128) void k_agg1p2(const int* __restrict__ nbr, const int* __restrict__ cnt,
                                                const float* __restrict__ h1p, const float* __restrict__ e1s,
                                                const float* __restrict__ e1d, const float* __restrict__ w2,
                                                const float* __restrict__ as2, const float* __restrict__ ad2,
                                                float* __restrict__ h2p, float* __restrict__ e2s,
                                                float* __restrict__ e2d)
{
    int bid = blockIdx.x;
    int xcd = bid & 7, g = bid >> 3;          // 16000 = 8 * 2000
    int b = (g / NN) * 8 + xcd;               // this XCD's 4 batches
    int n = g % NN;
    int row = b * NN + n;
    int t = threadIdx.x;
    int wv = t >> 6, lw = t & 63;             // wave id, lane-in-wave
    int h = t >> 4, o = t & 15;
    int half = t >> 6, o2 = t & 63;
    __shared__ int nb_s[2][MAXK];             // per-wave copy
    __shared__ float p_s[NHEAD][MAXK + 4];    // stride 132: heads on distinct banks
    __shared__ __align__(16) float hc[128];
    __shared__ float part[128];
    // unconditional loads: nbr (both slots) and cnt issue in parallel
    int nbA = nbr[(size_t)row * MAXK + lw];
    int nbB = nbr[(size_t)row * MAXK + lw + 64];
    int K = cnt[row];
    nb_s[wv][lw] = nbA;
    nb_s[wv][lw + 64] = nbB;
    // prefetch first 8 neighbors' feature (this thread's channel); clamp poisons to stay in-bounds
    const float* hp = h1p + (size_t)b * NN * 128 + t;
    int q0 = __shfl(nbA, 0), q1 = __shfl(nbA, 1), q2 = __shfl(nbA, 2), q3 = __shfl(nbA, 3);
    int q4 = __shfl(nbA, 4), q5 = __shfl(nbA, 5), q6 = __shfl(nbA, 6), q7 = __shfl(nbA, 7);
    q0 = (unsigned)q0 < NN ? q0 : 0; q1 = (unsigned)q1 < NN ? q1 : 0;
    q2 = (unsigned)q2 < NN ? q2 : 0; q3 = (unsigned)q3 < NN ? q3 : 0;
    q4 = (unsigned)q4 < NN ? q4 : 0; q5 = (unsigned)q5 < NN ? q5 : 0;
    q6 = (unsigned)q6 < NN ? q6 : 0; q7 = (unsigned)q7 < NN ? q7 : 0;
    float f0 = hp[(size_t)q0 * 128], f1 = hp[(size_t)q1 * 128];
    float f2 = hp[(size_t)q2 * 128], f3 = hp[(size_t)q3 * 128];
    float f4 = hp[(size_t)q4 * 128], f5 = hp[(size_t)q5 * 128];
    float f6 = hp[(size_t)q6 * 128], f7 = hp[(size_t)q7 * 128];
    // ---- e-phase (unchanged) ----
    float es = e1s[(size_t)row * 8 + h];
    float r[8];
    float mx = -1e30f;
#pragma unroll
    for (int j = 0; j < 8; ++j) {
        int k = o + j * 16;
        if (k < K) {
            float e = es + e1d[(size_t)(b * NN + nb_s[wv][k]) * 8 + h];
            e = e > 0.f ? e : 0.2f * e;
            r[j] = e;
            mx = fmaxf(mx, e);
        }
    }
#pragma unroll
    for (int m = 1; m < 16; m <<= 1) mx = fmaxf(mx, __shfl_xor(mx, m));
    float sum = 0.f;
#pragma unroll
    for (int j = 0; j < 8; ++j) {
        int k = o + j * 16;
        if (k < K) { float v = __expf(r[j] - mx); r[j] = v; sum += v; }
    }
#pragma unroll
    for (int m = 1; m < 16; m <<= 1) sum += __shfl_xor(sum, m);
    float inv = 1.f / sum;
#pragma unroll
    for (int j = 0; j < 8; ++j) {
        int k = o + j * 16;
        if (k < K) p_s[h][k] = r[j] * inv;    // head h: same-wave producer & consumer
    }
    // ---- gather: first group from prefetched regs (K>=8: identical FP order), rest as before ----
    float acc = 0.f;
    int k = 0;
    if (K >= 8) {
        acc += p_s[h][0] * f0;
        acc += p_s[h][1] * f1;
        acc += p_s[h][2] * f2;
        acc += p_s[h][3] * f3;
        acc += p_s[h][4] * f4;
        acc += p_s[h][5] * f5;
        acc += p_s[h][6] * f6;
        acc += p_s[h][7] * f7;
        k = 8;
    }
    for (; k + 8 <= K; k += 8) {
        float a0 = hp[(size_t)nb_s[wv][k] * 128];
        float a1 = hp[(size_t)nb_s[wv][k + 1] * 128];
        float a2 = hp[(size_t)nb_s[wv][k + 2] * 128];
        float a3 = hp[(size_t)nb_s[wv][k + 3] * 128];
        float a4 = hp[(size_t)nb_s[wv][k + 4] * 128];
        float a5 = hp[(size_t)nb_s[wv][k + 5] * 128];
        float a6 = hp[(size_t)nb_s[wv][k + 6] * 128];
        float a7 = hp[(size_t)nb_s[wv][k + 7] * 128];
        acc += p_s[h][k] * a0;
        acc += p_s[h][k + 1] * a1;
        acc += p_s[h][k + 2] * a2;
        acc += p_s[h][k + 3] * a3;
        acc += p_s[h][k + 4] * a4;
        acc += p_s[h][k + 5] * a5;
        acc += p_s[h][k + 6] * a6;
        acc += p_s[h][k + 7] * a7;
    }
    for (; k < K; ++k) acc += p_s[h][k] * hp[(size_t)nb_s[wv][k] * 128];
    hc[t] = acc > 0.f ? acc : expm1f(acc);     // ELU -> h1cat row, LDS only (same-wave consumer)
    // ---- streamed proj2 matvec (own wave's hc slice, no barrier) ----
    const float* wbase = w2 + (size_t)(half * 64) * 64 + o2;
    float acc2 = 0.f;
#pragma unroll
    for (int j4 = 0; j4 < 16; ++j4) {
        float4 hv = *(const float4*)&hc[half * 64 + j4 * 4];
        acc2 += hv.x * wbase[(j4 * 4 + 0) * 64] + hv.y * wbase[(j4 * 4 + 1) * 64]
              + hv.z * wbase[(j4 * 4 + 2) * 64] + hv.w * wbase[(j4 * 4 + 3) * 64];
    }
    part[t] = acc2;
    __syncthreads();                           // the one real cross-wave exchange
    if (half == 0) {
        float val = acc2 + part[64 + o2];
        h2p[(size_t)row * 64 + o2] = val;
        float vs = val * as2[o2], vd = val * ad2[o2];
#pragma unroll
        for (int m = 1; m < 64; m <<= 1) { vs += __shfl_xor(vs, m); vd += __shfl_xor(vd, m); }
        if (o2 == 0) { e2s[row] = vs; e2d[row] = vd; }
    }
}

// ---------------- K2: layer-2 sparse aggregate (4000 blocks x 256thr, 1 row/wave, barrier-free) ----------------
// Same latency cuts: unconditional nbr loads + first-8 h2p prefetch under the softmax.
__global__ __launch_bounds__(256) void k_agg2(const int* __restrict__ nbr, const int* __restrict__ cnt,
                                              const float* __restrict__ h2p, const float* __restrict__ e2s,
                                              const float* __restrict__ e2d, const float* __restrict__ aw,
                                              float* __restrict__ xc, float* __restrict__ sc,
                                              float* __restrict__ root_dot)
{
    int bid = blockIdx.x;
    int w = threadIdx.x >> 6, t = threadIdx.x & 63;
    int xcd = bid & 7, g = bid >> 3;          // 4000 = 8 * 500
    int b = (g / 125) * 8 + xcd;              // this XCD's 4 batches
    int n = (g % 125) * 4 + w;                // 4 consecutive rows, one per wave
    int row = b * NN + n;
    __shared__ int nb_s[4][MAXK];
    __shared__ float p_s[4][MAXK];
    if (n >= NVALID) { xc[(size_t)row * 64 + t] = 0.f; return; }   // padded rows exactly 0
    // unconditional loads: nbr (both slots) and cnt issue in parallel
    int nbA = nbr[(size_t)row * MAXK + t];
    int nbB = nbr[(size_t)row * MAXK + t + 64];
    int K = cnt[row];
    nb_s[w][t] = nbA;
    nb_s[w][t + 64] = nbB;
    // prefetch first 8 neighbors' h2p feature (this lane's channel); clamped addresses
    const float* h2b = h2p + (size_t)b * NN * 64 + t;
    int q0 = __shfl(nbA, 0), q1 = __shfl(nbA, 1), q2 = __shfl(nbA, 2), q3 = __shfl(nbA, 3);
    int q4 = __shfl(nbA, 4), q5 = __shfl(nbA, 5), q6 = __shfl(nbA, 6), q7 = __shfl(nbA, 7);
    q0 = (unsigned)q0 < NN ? q0 : 0; q1 = (unsigned)q1 < NN ? q1 : 0;
    q2 = (unsigned)q2 < NN ? q2 : 0; q3 = (unsigned)q3 < NN ? q3 : 0;
    q4 = (unsigned)q4 < NN ? q4 : 0; q5 = (unsigned)q5 < NN ? q5 : 0;
    q6 = (unsigned)q6 < NN ? q6 : 0; q7 = (unsigned)q7 < NN ? q7 : 0;
    float f0 = h2b[(size_t)q0 * 64], f1 = h2b[(size_t)q1 * 64];
    float f2 = h2b[(size_t)q2 * 64], f3 = h2b[(size_t)q3 * 64];
    float f4 = h2b[(size_t)q4 * 64], f5 = h2b[(size_t)q5 * 64];
    float f6 = h2b[(size_t)q6 * 64], f7 = h2b[(size_t)q7 * 64];
    // ---- e-phase + softmax (unchanged) ----
    float es = e2s[row];
    float r0 = -1e30f, r1 = -1e30f;
    if (t < K) {
        float e = es + e2d[b * NN + nbA];
        r0 = e > 0.f ? e : 0.2f * e;
    }
    if (t + 64 < K) {
        float e = es + e2d[b * NN + nbB];
        r1 = e > 0.f ? e : 0.2f * e;
    }
    float mx = fmaxf(r0, r1);
#pragma unroll
    for (int m = 1; m < 64; m <<= 1) mx = fmaxf(mx, __shfl_xor(mx, m));
    float v0 = (t < K) ? __expf(r0 - mx) : 0.f;
    float v1 = (t + 64 < K) ? __expf(r1 - mx) : 0.f;
    float sum = v0 + v1;
#pragma unroll
    for (int m = 1; m < 64; m <<= 1) sum += __shfl_xor(sum, m);
    float inv = 1.f / sum;
    if (t < K) p_s[w][t] = v0 * inv;
    if (t + 64 < K) p_s[w][t + 64] = v1 * inv;
    // ---- gather: first group from prefetched regs, rest as before (FP order preserved) ----
    float acc = 0.f;
    int k = 0;
    if (K >= 8) {
        acc += p_s[w][0] * f0;
        acc += p_s[w][1] * f1;
        acc += p_s[w][2] * f2;
        acc += p_s[w][3] * f3;
        acc += p_s[w][4] * f4;
        acc += p_s[w][5] * f5;
        acc += p_s[w][6] * f6;
        acc += p_s[w][7] * f7;
        k = 8;
    }
    for (; k + 8 <= K; k += 8) {
        float a0 = h2b[(size_t)nb_s[w][k] * 64];
        float a1 = h2b[(size_t)nb_s[w][k + 1] * 64];
        float a2 = h2b[(size_t)nb_s[w][k + 2] * 64];
        float a3 = h2b[(size_t)nb_s[w][k + 3] * 64];
        float a4 = h2b[(size_t)nb_s[w][k + 4] * 64];
        float a5 = h2b[(size_t)nb_s[w][k + 5] * 64];
        float a6 = h2b[(size_t)nb_s[w][k + 6] * 64];
        float a7 = h2b[(size_t)nb_s[w][k + 7] * 64];
        acc += p_s[w][k] * a0;
        acc += p_s[w][k + 1] * a1;
        acc += p_s[w][k + 2] * a2;
        acc += p_s[w][k + 3] * a3;
        acc += p_s[w][k + 4] * a4;
        acc += p_s[w][k + 5] * a5;
        acc += p_s[w][k + 6] * a6;
        acc += p_s[w][k + 7] * a7;
    }
    for (; k < K; ++k) acc += p_s[w][k] * h2b[(size_t)nb_s[w][k] * 64];
    xc[(size_t)row * 64 + t] = acc;
    // fused: score_part[row] = dot(xc_row, aw[0:64])
    float v = acc * aw[t];
#pragma unroll
    for (int m = 1; m < 64; m <<= 1) v += __shfl_xor(v, m);
    if (t == 0) sc[row] = v;
    if (n == 0) {   // root-feature dot with aw[64:128]
        float v2 = acc * aw[64 + t];
#pragma unroll
        for (int m = 1; m < 64; m <<= 1) v2 += __shfl_xor(v2, m);
        if (t == 0) root_dot[b] = v2;
    }
}

// ---------------- K3: softmax over nodes + pooled output (1024 thr, 16 waves) ----------------
__global__ __launch_bounds__(1024) void k_pool(const float* __restrict__ xc, const float* __restrict__ sc,
                                               const float* __restrict__ root_dot, float* __restrict__ out)
{
    int b = blockIdx.x;
    int t = threadIdx.x, w = t >> 6, lane = t & 63;
    __shared__ float attn_s[NN];
    __shared__ float red[16];
    __shared__ float part[16][64];
    const float* xb = xc + (size_t)b * NN * 64;
    float rd = root_dot[b];
    float s = NEG_INF;
    if (t < NVALID) {
        s = sc[b * NN + t] + rd;
        if (s == 0.f) s = NEG_INF;      // masked_fill(score==0); padded rows stay NEG_INF
    }
    float mx = s;
#pragma unroll
    for (int m = 1; m < 64; m <<= 1) mx = fmaxf(mx, __shfl_xor(mx, m));
    if (lane == 0) red[w] = mx;
    __syncthreads();
    mx = red[0];
#pragma unroll
    for (int i = 1; i < 16; ++i) mx = fmaxf(mx, red[i]);
    float e = (t < NN) ? __expf(s - mx) : 0.f;
    float sum = e;
#pragma unroll
    for (int m = 1; m < 64; m <<= 1) sum += __shfl_xor(sum, m);
    __syncthreads();
    if (lane == 0) red[w] = sum;
    __syncthreads();
    sum = 0.f;
#pragma unroll
    for (int i = 0; i < 16; ++i) sum += red[i];
    float inv = 1.f / sum;
    if (t < NN) {
        float a = e * inv;
        out[NB * 64 + b * NN + t] = a;   // attn output
        attn_s[t] = a;
    }
    __syncthreads();
    float acc = 0.f;
    for (int n = w; n < NN; n += 16) acc += attn_s[n] * xb[(size_t)n * 64 + lane];
    part[w][lane] = acc;
    __syncthreads();
    if (t < 64) {
        float v = 0.f;
#pragma unroll
        for (int i = 0; i < 16; ++i) v += part[i][t];
        out[b * 64 + t] = v;
    }
}

extern "C" void kernel_launch(void* const* d_in, const int* in_sizes, int n_in,
                              void* d_out, int out_size, void* d_ws, size_t ws_size,
                              hipStream_t stream) {
    const float* x   = (const float*)d_in[0];
    const float* A   = (const float*)d_in[1];
    const float* w1  = (const float*)d_in[4];
    const float* as1 = (const float*)d_in[5];
    const float* ad1 = (const float*)d_in[6];
    const float* w2  = (const float*)d_in[7];
    const float* as2 = (const float*)d_in[8];
    const float* ad2 = (const float*)d_in[9];
    const float* aw  = (const float*)d_in[10];
    float* out = (float*)d_out;

    char* ws = (char*)d_ws;
    int* nbr = (int*)ws;                               // [16000][128]
    int* cnt = (int*)(ws + (size_t)16000 * 128 * 4);   // [16000]
    float* f = (float*)(ws + (size_t)16000 * 129 * 4);
    float* h1p   = f;  f += (size_t)NB * NN * 128;     // [b][n][h*16+o]
    float* e1s   = f;  f += (size_t)NB * NN * NHEAD;   // [b][n][h]
    float* e1d   = f;  f += (size_t)NB * NN * NHEAD;
    float* h2p   = f;  f += (size_t)NB * NN * 64;
    float* e2s   = f;  f += (size_t)NB * NN;
    float* e2d   = f;  f += (size_t)NB * NN;
    float* xc    = f;  f += (size_t)NB * NN * 64;
    float* sc    = f;  f += (size_t)NB * NN;
    float* rootd = f;  f += NB;

    hipLaunchKernelGGL(k_pre,    dim3(5024),    dim3(256),  0, stream, A, nbr, cnt, x, w1, as1, ad1, h1p, e1s, e1d);
    hipLaunchKernelGGL(k_agg1p2, dim3(NB * NN), dim3(128),  0, stream, nbr, cnt, h1p, e1s, e1d, w2, as2, ad2, h2p, e2s, e2d);
    hipLaunchKernelGGL(k_agg2,   dim3(4000),    dim3(256),  0, stream, nbr, cnt, h2p, e2s, e2d, aw, xc, sc, rootd);
    hipLaunchKernelGGL(k_pool,   dim3(NB),      dim3(1024), 0, stream, xc, sc, rootd, out);
}

// Round 14
// 154.909 us; speedup vs baseline: 1.0037x; 1.0037x over previous
//
#include <hip/hip_runtime.h>

#define NB 32
#define NN 500
#define HIN 64
#define HHID 16
#define NHEAD 8
#define NVALID 400
#define MAXK 128
#define NEG_INF -1e20f

// ---------------- K0: fused layer-1 projection (blocks 0..1023) + neighbor-list build (blocks 1024..5023) ----
__global__ __launch_bounds__(256) void k_pre(const float* __restrict__ A,
                                             int* __restrict__ nbr, int* __restrict__ cnt,
                                             const float* __restrict__ x, const float* __restrict__ w1,
                                             const float* __restrict__ as1, const float* __restrict__ ad1,
                                             float* __restrict__ h1p, float* __restrict__ e1s,
                                             float* __restrict__ e1d)
{
    int bid = blockIdx.x;
    if (bid >= 1024) {
        // ---- neighbor build: 4 rows per block, one wave per row ----
        int row = (bid - 1024) * 4 + (threadIdx.x >> 6);   // b*NN + n
        int lane = threadIdx.x & 63;
        const float4* arow4 = (const float4*)(A + (size_t)row * NN);  // 125 float4, 16B aligned
        int* np = nbr + (size_t)row * MAXK;
        int c = 0;
#pragma unroll
        for (int it = 0; it < 2; ++it) {
            int idx = it * 64 + lane;
            float4 av;
            if (idx < 125) av = arow4[idx];
            else { av.x = av.y = av.z = av.w = 0.f; }
            bool v0 = av.x > 0.f, v1 = av.y > 0.f, v2 = av.z > 0.f, v3 = av.w > 0.f;
            unsigned long long b0 = __ballot(v0), b1 = __ballot(v1);
            unsigned long long b2 = __ballot(v2), b3 = __ballot(v3);
            unsigned long long below = (1ull << lane) - 1ull;
            int p = c + __popcll(b0 & below) + __popcll(b1 & below)
                      + __popcll(b2 & below) + __popcll(b3 & below);
            int col = idx * 4;
            if (v0 && p < MAXK) np[p] = col;     p += (int)v0;
            if (v1 && p < MAXK) np[p] = col + 1; p += (int)v1;
            if (v2 && p < MAXK) np[p] = col + 2; p += (int)v2;
            if (v3 && p < MAXK) np[p] = col + 3; p += (int)v3;
            c += (int)(__popcll(b0) + __popcll(b1) + __popcll(b2) + __popcll(b3));
        }
        if (lane == 0) cnt[row] = c < MAXK ? c : MAXK;
        return;
    }
    // ---- layer-1 projection (single-stage) ----
    int pb = bid;
    int b = pb >> 5, chunk = pb & 31;
    int t = threadIdx.x, slot = t >> 7, lane = t & 127;
    int h = lane >> 4, o = lane & 15;
    float wreg[64];
#pragma unroll
    for (int f = 0; f < 64; ++f) wreg[f] = w1[h * 1024 + f * 16 + o];
    float as_r = as1[h * 16 + o], ad_r = ad1[h * 16 + o];
    __shared__ __align__(16) float xs[16][64];
    {
        int node = chunk * 16 + (t >> 4);
        float4 v = make_float4(0.f, 0.f, 0.f, 0.f);
        if (node < NN) v = *(const float4*)&x[(size_t)(b * NN + node) * HIN + ((t * 4) & 63)];
        *(float4*)&xs[t >> 4][(t * 4) & 63] = v;
    }
    __syncthreads();
    for (int i = 0; i < 8; ++i) {
        int n = chunk * 16 + i * 2 + slot;
        if (n < NN) {
            const float* xrow = xs[i * 2 + slot];
            float acc = 0.f;
#pragma unroll
            for (int f4 = 0; f4 < 16; ++f4) {
                float4 xv = *(const float4*)&xrow[f4 * 4];
                acc += xv.x * wreg[f4 * 4] + xv.y * wreg[f4 * 4 + 1]
                     + xv.z * wreg[f4 * 4 + 2] + xv.w * wreg[f4 * 4 + 3];
            }
            h1p[(size_t)(b * NN + n) * 128 + lane] = acc;      // [b][n][h*16+o]
            float vs = acc * as_r, vd = acc * ad_r;
#pragma unroll
            for (int m = 1; m < 16; m <<= 1) { vs += __shfl_xor(vs, m); vd += __shfl_xor(vd, m); }
            if (o == 0) {
                e1s[(size_t)(b * NN + n) * 8 + h] = vs;        // [b][n][h]
                e1d[(size_t)(b * NN + n) * 8 + h] = vd;
            }
        }
    }
}

// ---------------- K1: fused layer-1 aggregate + ELU + streamed layer-2 projection ----------------
// R12 + e-phase loads made UNCONDITIONAL (clamped poison indices, VALU predicated on k<K):
// all 8 e1d scattered loads issue together -> one exposed latency instead of up to 8.
__global__ __launch_bounds__(128) void k_agg1p2(const int* __restrict__ nbr, const int* __restrict__ cnt,
                                                const float* __restrict__ h1p, const float* __restrict__ e1s,
                                                const float* __restrict__ e1d, const float* __restrict__ w2,
                                                const float* __restrict__ as2, const float* __restrict__ ad2,
                                                float* __restrict__ h2p, float* __restrict__ e2s,
                                                float* __restrict__ e2d)
{
    int bid = blockIdx.x;
    int xcd = bid & 7, g = bid >> 3;          // 16000 = 8 * 2000
    int b = (g / NN) * 8 + xcd;               // this XCD's 4 batches
    int n = g % NN;
    int row = b * NN + n;
    int t = threadIdx.x;
    int wv = t >> 6, lw = t & 63;             // wave id, lane-in-wave
    int h = t >> 4, o = t & 15;
    int half = t >> 6, o2 = t & 63;
    __shared__ int nb_s[2][MAXK];             // per-wave copy
    __shared__ float p_s[NHEAD][MAXK + 4];    // stride 132: heads on distinct banks
    __shared__ __align__(16) float hc[128];
    __shared__ float part[128];
    // unconditional loads: nbr (both slots) and cnt issue in parallel
    int nbA = nbr[(size_t)row * MAXK + lw];
    int nbB = nbr[(size_t)row * MAXK + lw + 64];
    int K = cnt[row];
    nb_s[wv][lw] = nbA;
    nb_s[wv][lw + 64] = nbB;
    // prefetch first 8 neighbors' feature (this thread's channel); clamp poisons to stay in-bounds
    const float* hp = h1p + (size_t)b * NN * 128 + t;
    int q0 = __shfl(nbA, 0), q1 = __shfl(nbA, 1), q2 = __shfl(nbA, 2), q3 = __shfl(nbA, 3);
    int q4 = __shfl(nbA, 4), q5 = __shfl(nbA, 5), q6 = __shfl(nbA, 6), q7 = __shfl(nbA, 7);
    q0 = (unsigned)q0 < NN ? q0 : 0; q1 = (unsigned)q1 < NN ? q1 : 0;
    q2 = (unsigned)q2 < NN ? q2 : 0; q3 = (unsigned)q3 < NN ? q3 : 0;
    q4 = (unsigned)q4 < NN ? q4 : 0; q5 = (unsigned)q5 < NN ? q5 : 0;
    q6 = (unsigned)q6 < NN ? q6 : 0; q7 = (unsigned)q7 < NN ? q7 : 0;
    float f0 = hp[(size_t)q0 * 128], f1 = hp[(size_t)q1 * 128];
    float f2 = hp[(size_t)q2 * 128], f3 = hp[(size_t)q3 * 128];
    float f4 = hp[(size_t)q4 * 128], f5 = hp[(size_t)q5 * 128];
    float f6 = hp[(size_t)q6 * 128], f7 = hp[(size_t)q7 * 128];
    // ---- e-phase: unconditional clamped loads, then predicated VALU (bitwise-identical result) ----
    float es = e1s[(size_t)row * 8 + h];
    float ev[8];
#pragma unroll
    for (int j = 0; j < 8; ++j) {
        int k = o + j * 16;                    // always < MAXK
        int nb = nb_s[wv][k];
        nb = (unsigned)nb < NN ? nb : 0;       // clamp poison (entries >= K)
        ev[j] = e1d[(size_t)(b * NN + nb) * 8 + h];
    }
    float r[8];
    float mx = -1e30f;
#pragma unroll
    for (int j = 0; j < 8; ++j) {
        int k = o + j * 16;
        if (k < K) {
            float e = es + ev[j];
            e = e > 0.f ? e : 0.2f * e;
            r[j] = e;
            mx = fmaxf(mx, e);
        }
    }
#pragma unroll
    for (int m = 1; m < 16; m <<= 1) mx = fmaxf(mx, __shfl_xor(mx, m));
    float sum = 0.f;
#pragma unroll
    for (int j = 0; j < 8; ++j) {
        int k = o + j * 16;
        if (k < K) { float v = __expf(r[j] - mx); r[j] = v; sum += v; }
    }
#pragma unroll
    for (int m = 1; m < 16; m <<= 1) sum += __shfl_xor(sum, m);
    float inv = 1.f / sum;
#pragma unroll
    for (int j = 0; j < 8; ++j) {
        int k = o + j * 16;
        if (k < K) p_s[h][k] = r[j] * inv;    // head h: same-wave producer & consumer
    }
    // ---- gather: first group from prefetched regs (K>=8: identical FP order), rest as before ----
    float acc = 0.f;
    int k = 0;
    if (K >= 8) {
        acc += p_s[h][0] * f0;
        acc += p_s[h][1] * f1;
        acc += p_s[h][2] * f2;
        acc += p_s[h][3] * f3;
        acc += p_s[h][4] * f4;
        acc += p_s[h][5] * f5;
        acc += p_s[h][6] * f6;
        acc += p_s[h][7] * f7;
        k = 8;
    }
    for (; k + 8 <= K; k += 8) {
        float a0 = hp[(size_t)nb_s[wv][k] * 128];
        float a1 = hp[(size_t)nb_s[wv][k + 1] * 128];
        float a2 = hp[(size_t)nb_s[wv][k + 2] * 128];
        float a3 = hp[(size_t)nb_s[wv][k + 3] * 128];
        float a4 = hp[(size_t)nb_s[wv][k + 4] * 128];
        float a5 = hp[(size_t)nb_s[wv][k + 5] * 128];
        float a6 = hp[(size_t)nb_s[wv][k + 6] * 128];
        float a7 = hp[(size_t)nb_s[wv][k + 7] * 128];
        acc += p_s[h][k] * a0;
        acc += p_s[h][k + 1] * a1;
        acc += p_s[h][k + 2] * a2;
        acc += p_s[h][k + 3] * a3;
        acc += p_s[h][k + 4] * a4;
        acc += p_s[h][k + 5] * a5;
        acc += p_s[h][k + 6] * a6;
        acc += p_s[h][k + 7] * a7;
    }
    for (; k < K; ++k) acc += p_s[h][k] * hp[(size_t)nb_s[wv][k] * 128];
    hc[t] = acc > 0.f ? acc : expm1f(acc);     // ELU -> h1cat row, LDS only (same-wave consumer)
    // ---- streamed proj2 matvec (own wave's hc slice, no barrier) ----
    const float* wbase = w2 + (size_t)(half * 64) * 64 + o2;
    float acc2 = 0.f;
#pragma unroll
    for (int j4 = 0; j4 < 16; ++j4) {
        float4 hv = *(const float4*)&hc[half * 64 + j4 * 4];
        acc2 += hv.x * wbase[(j4 * 4 + 0) * 64] + hv.y * wbase[(j4 * 4 + 1) * 64]
              + hv.z * wbase[(j4 * 4 + 2) * 64] + hv.w * wbase[(j4 * 4 + 3) * 64];
    }
    part[t] = acc2;
    __syncthreads();                           // the one real cross-wave exchange
    if (half == 0) {
        float val = acc2 + part[64 + o2];
        h2p[(size_t)row * 64 + o2] = val;
        float vs = val * as2[o2], vd = val * ad2[o2];
#pragma unroll
        for (int m = 1; m < 64; m <<= 1) { vs += __shfl_xor(vs, m); vd += __shfl_xor(vd, m); }
        if (o2 == 0) { e2s[row] = vs; e2d[row] = vd; }
    }
}

// ---------------- K2: layer-2 sparse aggregate (4000 blocks x 256thr, 1 row/wave, barrier-free) ----------------
// e-loads made unconditional (clamped), VALU predicated; rest unchanged from R12.
__global__ __launch_bounds__(256) void k_agg2(const int* __restrict__ nbr, const int* __restrict__ cnt,
                                              const float* __restrict__ h2p, const float* __restrict__ e2s,
                                              const float* __restrict__ e2d, const float* __restrict__ aw,
                                              float* __restrict__ xc, float* __restrict__ sc,
                                              float* __restrict__ root_dot)
{
    int bid = blockIdx.x;
    int w = threadIdx.x >> 6, t = threadIdx.x & 63;
    int xcd = bid & 7, g = bid >> 3;          // 4000 = 8 * 500
    int b = (g / 125) * 8 + xcd;              // this XCD's 4 batches
    int n = (g % 125) * 4 + w;                // 4 consecutive rows, one per wave
    int row = b * NN + n;
    __shared__ int nb_s[4][MAXK];
    __shared__ float p_s[4][MAXK];
    if (n >= NVALID) { xc[(size_t)row * 64 + t] = 0.f; return; }   // padded rows exactly 0
    // unconditional loads: nbr (both slots) and cnt issue in parallel
    int nbA = nbr[(size_t)row * MAXK + t];
    int nbB = nbr[(size_t)row * MAXK + t + 64];
    int K = cnt[row];
    nb_s[w][t] = nbA;
    nb_s[w][t + 64] = nbB;
    int cA = (unsigned)nbA < NN ? nbA : 0;    // clamped copies for unconditional loads
    int cB = (unsigned)nbB < NN ? nbB : 0;
    // prefetch first 8 neighbors' h2p feature (this lane's channel); clamped addresses
    const float* h2b = h2p + (size_t)b * NN * 64 + t;
    int q0 = __shfl(cA, 0), q1 = __shfl(cA, 1), q2 = __shfl(cA, 2), q3 = __shfl(cA, 3);
    int q4 = __shfl(cA, 4), q5 = __shfl(cA, 5), q6 = __shfl(cA, 6), q7 = __shfl(cA, 7);
    float f0 = h2b[(size_t)q0 * 64], f1 = h2b[(size_t)q1 * 64];
    float f2 = h2b[(size_t)q2 * 64], f3 = h2b[(size_t)q3 * 64];
    float f4 = h2b[(size_t)q4 * 64], f5 = h2b[(size_t)q5 * 64];
    float f6 = h2b[(size_t)q6 * 64], f7 = h2b[(size_t)q7 * 64];
    // ---- e-phase: unconditional clamped loads, predicated VALU ----
    float es = e2s[row];
    float eA = e2d[b * NN + cA];
    float eB = e2d[b * NN + cB];
    float r0 = -1e30f, r1 = -1e30f;
    if (t < K) {
        float e = es + eA;
        r0 = e > 0.f ? e : 0.2f * e;
    }
    if (t + 64 < K) {
        float e = es + eB;
        r1 = e > 0.f ? e : 0.2f * e;
    }
    float mx = fmaxf(r0, r1);
#pragma unroll
    for (int m = 1; m < 64; m <<= 1) mx = fmaxf(mx, __shfl_xor(mx, m));
    float v0 = (t < K) ? __expf(r0 - mx) : 0.f;
    float v1 = (t + 64 < K) ? __expf(r1 - mx) : 0.f;
    float sum = v0 + v1;
#pragma unroll
    for (int m = 1; m < 64; m <<= 1) sum += __shfl_xor(sum, m);
    float inv = 1.f / sum;
    if (t < K) p_s[w][t] = v0 * inv;
    if (t + 64 < K) p_s[w][t + 64] = v1 * inv;
    // ---- gather: first group from prefetched regs, rest as before (FP order preserved) ----
    float acc = 0.f;
    int k = 0;
    if (K >= 8) {
        acc += p_s[w][0] * f0;
        acc += p_s[w][1] * f1;
        acc += p_s[w][2] * f2;
        acc += p_s[w][3] * f3;
        acc += p_s[w][4] * f4;
        acc += p_s[w][5] * f5;
        acc += p_s[w][6] * f6;
        acc += p_s[w][7] * f7;
        k = 8;
    }
    for (; k + 8 <= K; k += 8) {
        float a0 = h2b[(size_t)nb_s[w][k] * 64];
        float a1 = h2b[(size_t)nb_s[w][k + 1] * 64];
        float a2 = h2b[(size_t)nb_s[w][k + 2] * 64];
        float a3 = h2b[(size_t)nb_s[w][k + 3] * 64];
        float a4 = h2b[(size_t)nb_s[w][k + 4] * 64];
        float a5 = h2b[(size_t)nb_s[w][k + 5] * 64];
        float a6 = h2b[(size_t)nb_s[w][k + 6] * 64];
        float a7 = h2b[(size_t)nb_s[w][k + 7] * 64];
        acc += p_s[w][k] * a0;
        acc += p_s[w][k + 1] * a1;
        acc += p_s[w][k + 2] * a2;
        acc += p_s[w][k + 3] * a3;
        acc += p_s[w][k + 4] * a4;
        acc += p_s[w][k + 5] * a5;
        acc += p_s[w][k + 6] * a6;
        acc += p_s[w][k + 7] * a7;
    }
    for (; k < K; ++k) acc += p_s[w][k] * h2b[(size_t)nb_s[w][k] * 64];
    xc[(size_t)row * 64 + t] = acc;
    // fused: score_part[row] = dot(xc_row, aw[0:64])
    float v = acc * aw[t];
#pragma unroll
    for (int m = 1; m < 64; m <<= 1) v += __shfl_xor(v, m);
    if (t == 0) sc[row] = v;
    if (n == 0) {   // root-feature dot with aw[64:128]
        float v2 = acc * aw[64 + t];
#pragma unroll
        for (int m = 1; m < 64; m <<= 1) v2 += __shfl_xor(v2, m);
        if (t == 0) root_dot[b] = v2;
    }
}

// ---------------- K3: softmax over nodes + pooled output (1024 thr, 16 waves) ----------------
__global__ __launch_bounds__(1024) void k_pool(const float* __restrict__ xc, const float* __restrict__ sc,
                                               const float* __restrict__ root_dot, float* __restrict__ out)
{
    int b = blockIdx.x;
    int t = threadIdx.x, w = t >> 6, lane = t & 63;
    __shared__ float attn_s[NN];
    __shared__ float red[16];
    __shared__ float part[16][64];
    const float* xb = xc + (size_t)b * NN * 64;
    float rd = root_dot[b];
    float s = NEG_INF;
    if (t < NVALID) {
        s = sc[b * NN + t] + rd;
        if (s == 0.f) s = NEG_INF;      // masked_fill(score==0); padded rows stay NEG_INF
    }
    float mx = s;
#pragma unroll
    for (int m = 1; m < 64; m <<= 1) mx = fmaxf(mx, __shfl_xor(mx, m));
    if (lane == 0) red[w] = mx;
    __syncthreads();
    mx = red[0];
#pragma unroll
    for (int i = 1; i < 16; ++i) mx = fmaxf(mx, red[i]);
    float e = (t < NN) ? __expf(s - mx) : 0.f;
    float sum = e;
#pragma unroll
    for (int m = 1; m < 64; m <<= 1) sum += __shfl_xor(sum, m);
    __syncthreads();
    if (lane == 0) red[w] = sum;
    __syncthreads();
    sum = 0.f;
#pragma unroll
    for (int i = 0; i < 16; ++i) sum += red[i];
    float inv = 1.f / sum;
    if (t < NN) {
        float a = e * inv;
        out[NB * 64 + b * NN + t] = a;   // attn output
        attn_s[t] = a;
    }
    __syncthreads();
    float acc = 0.f;
    for (int n = w; n < NN; n += 16) acc += attn_s[n] * xb[(size_t)n * 64 + lane];
    part[w][lane] = acc;
    __syncthreads();
    if (t < 64) {
        float v = 0.f;
#pragma unroll
        for (int i = 0; i < 16; ++i) v += part[i][t];
        out[b * 64 + t] = v;
    }
}

extern "C" void kernel_launch(void* const* d_in, const int* in_sizes, int n_in,
                              void* d_out, int out_size, void* d_ws, size_t ws_size,
                              hipStream_t stream) {
    const float* x   = (const float*)d_in[0];
    const float* A   = (const float*)d_in[1];
    const float* w1  = (const float*)d_in[4];
    const float* as1 = (const float*)d_in[5];
    const float* ad1 = (const float*)d_in[6];
    const float* w2  = (const float*)d_in[7];
    const float* as2 = (const float*)d_in[8];
    const float* ad2 = (const float*)d_in[9];
    const float* aw  = (const float*)d_in[10];
    float* out = (float*)d_out;

    char* ws = (char*)d_ws;
    int* nbr = (int*)ws;                               // [16000][128]
    int* cnt = (int*)(ws + (size_t)16000 * 128 * 4);   // [16000]
    float* f = (float*)(ws + (size_t)16000 * 129 * 4);
    float* h1p   = f;  f += (size_t)NB * NN * 128;     // [b][n][h*16+o]
    float* e1s   = f;  f += (size_t)NB * NN * NHEAD;   // [b][n][h]
    float* e1d   = f;  f += (size_t)NB * NN * NHEAD;
    float* h2p   = f;  f += (size_t)NB * NN * 64;
    float* e2s   = f;  f += (size_t)NB * NN;
    float* e2d   = f;  f += (size_t)NB * NN;
    float* xc    = f;  f += (size_t)NB * NN * 64;
    float* sc    = f;  f += (size_t)NB * NN;
    float* rootd = f;  f += NB;

    hipLaunchKernelGGL(k_pre,    dim3(5024),    dim3(256),  0, stream, A, nbr, cnt, x, w1, as1, ad1, h1p, e1s, e1d);
    hipLaunchKernelGGL(k_agg1p2, dim3(NB * NN), dim3(128),  0, stream, nbr, cnt, h1p, e1s, e1d, w2, as2, ad2, h2p, e2s, e2d);
    hipLaunchKernelGGL(k_agg2,   dim3(4000),    dim3(256),  0, stream, nbr, cnt, h2p, e2s, e2d, aw, xc, sc, rootd);
    hipLaunchKernelGGL(k_pool,   dim3(NB),      dim3(1024), 0, stream, xc, sc, rootd, out);
}